// Round 5
// baseline (804.625 us; speedup 1.0000x reference)
//
#include <hip/hip_runtime.h>
#include <hip/hip_bf16.h>
#include <math.h>

#define H 64
#define DM 128
#define GDIM 192      // 3*H
#define BSZ 32
#define SEQ 500
#define NROW (BSZ*SEQ)  // 16000
#define LIBN 2145
#define FFD 128
#define KPAD 2176     // 68*32 (theta K padded)
#define NKC 68        // K chunks of 32
#define NB 16         // batch elements per GRU block

typedef __attribute__((ext_vector_type(8))) short short8;   // bf16x8 MFMA operand
typedef __attribute__((ext_vector_type(4))) float f32x4;    // MFMA accumulator
typedef __attribute__((ext_vector_type(4))) unsigned u32x4;

__device__ __forceinline__ float sigf(float x) {
    return 1.0f / (1.0f + __expf(-x));
}
__device__ __forceinline__ float tanhfast(float x) {
    x = fminf(fmaxf(x, -15.0f), 15.0f);
    float t = __expf(-2.0f * x);
    return (1.0f - t) / (1.0f + t);
}
__device__ __forceinline__ short bf16r(float f) {   // fp32 -> bf16 rne
    unsigned u = __float_as_uint(f);
    unsigned r = (u + 0x7fffu + ((u >> 16) & 1u)) >> 16;
    return (short)r;
}

// ---------------- pack Wih0 (192,128) -> WTp[k4][g][e] for coalesced float4 loads ----
__global__ void pack_wih0(const float* __restrict__ w, float* __restrict__ wt) {
    int idx = blockIdx.x * 256 + threadIdx.x;
    if (idx >= GDIM * DM) return;
    int e  = idx & 3;
    int g  = (idx >> 2) % GDIM;
    int k4 = idx / (GDIM * 4);
    wt[idx] = w[g * DM + k4 * 4 + e];
}

// ---- prepack coef (2145x64, zero-pad to 2176) into bf16 B-fragment-linear order ----
__global__ void pack_coef_frag(const float* __restrict__ coef, short* __restrict__ cp) {
    int idx = blockIdx.x * 256 + threadIdx.x;           // 68*4*64*8 = 139264
    int j = idx & 7, lane = (idx >> 3) & 63, nt = (idx >> 9) & 3, kc = idx >> 11;
    int k = kc * 32 + ((lane >> 4) << 3) + j;
    int c = nt * 16 + (lane & 15);
    float v = (k < LIBN) ? coef[(size_t)k * H + c] : 0.0f;
    cp[idx] = bf16r(v);
}
// ---- W1 (128,64): B = W1^T (K=64,N=128) ----
__global__ void pack_w1_frag(const float* __restrict__ w1, short* __restrict__ wp) {
    int idx = blockIdx.x * 256 + threadIdx.x;           // 2*8*64*8 = 8192
    int j = idx & 7, lane = (idx >> 3) & 63, nt = (idx >> 9) & 7, kc = idx >> 12;
    int k = kc * 32 + ((lane >> 4) << 3) + j;
    int n = nt * 16 + (lane & 15);
    wp[idx] = bf16r(w1[(size_t)n * H + k]);
}
// ---- W2 (64,128): B = W2^T (K=128,N=64) ----
__global__ void pack_w2_frag(const float* __restrict__ w2, short* __restrict__ wp) {
    int idx = blockIdx.x * 256 + threadIdx.x;           // 4*4*64*8 = 8192
    int j = idx & 7, lane = (idx >> 3) & 63, nt = (idx >> 9) & 3, kc = idx >> 11;
    int k = kc * 32 + ((lane >> 4) << 3) + j;
    int n = nt * 16 + (lane & 15);
    wp[idx] = bf16r(w2[(size_t)n * FFD + k]);
}
// ---- GRU weight (192x64) -> bf16 A-frag order: [t(12)][kc(2)][lane(64)][j(8)] ----
// A[m][k]: m = 16t + (lane&15), k = kc*32 + (lane>>4)*8 + j
__global__ void pack_gruw_frag(const float* __restrict__ w, short* __restrict__ wp) {
    int idx = blockIdx.x * 256 + threadIdx.x;           // 12*2*64*8 = 12288
    if (idx >= 12288) return;
    int j = idx & 7, lane = (idx >> 3) & 63, kc = (idx >> 9) & 1, t = idx >> 10;
    int m = 16 * t + (lane & 15);
    int k = kc * 32 + ((lane >> 4) << 3) + j;
    wp[idx] = bf16r(w[(size_t)m * H + k]);
}

// ---------------- xp0 = x @ Wih0^T + bih0 : (16000,128)@(128,192) ------------------
__global__ __launch_bounds__(192, 2) void xp0_gemm(const float* __restrict__ x,
                                                   const float* __restrict__ wtp,
                                                   const float* __restrict__ bih0,
                                                   float* __restrict__ xp0) {
    __shared__ float xs[64][DM];
    int rb = blockIdx.x * 64;
    for (int idx = threadIdx.x; idx < 64 * 32; idx += 192) {
        int r = idx >> 5, k4 = idx & 31;
        ((f32x4*)xs[r])[k4] = ((const f32x4*)(x + (size_t)(rb + r) * DM))[k4];
    }
    __syncthreads();
    int g = threadIdx.x;
    float bias = bih0[g];
    float acc[64];
#pragma unroll
    for (int r = 0; r < 64; r++) acc[r] = bias;
    for (int k4 = 0; k4 < 32; k4++) {
        f32x4 w4 = ((const f32x4*)wtp)[k4 * GDIM + g];
#pragma unroll
        for (int r = 0; r < 64; r++) {
            f32x4 xv = ((f32x4*)xs[r])[k4];
            acc[r] += w4[0] * xv[0] + w4[1] * xv[1] + w4[2] * xv[2] + w4[3] * xv[3];
        }
    }
    for (int r = 0; r < 64; r++) xp0[(size_t)(rb + r) * GDIM + g] = acc[r];
}

// ---------------- MFMA 2-layer GRU scan: 16 batch/block, 8 waves ---------------------
// wave (g = wv>>2, w = wv&3): g=0 -> layer0 (Whh0@h0), g=1 -> layer1 (Wih1@h0 AND
// Whh1@h1). Rows {16w (r), 64+16w (z), 128+16w (n)} so r,z,n for hidden i land in the
// SAME lane (C row = quad*4+reg, col = batch). h state in LDS as bf16 in B-frag-ready
// layout (one ds_read_b128 per frag); fp32 recurrence value stays in registers.
// Double-buffered h -> single barrier per step. Layer 1 one step skewed.
__global__ __launch_bounds__(512) void gru_mfma(const float* __restrict__ xp0,
                                                const short* __restrict__ a0,
                                                const short* __restrict__ a1,
                                                const short* __restrict__ a2,
                                                const float* __restrict__ bhh0,
                                                const float* __restrict__ bih1,
                                                const float* __restrict__ bhh1,
                                                float* __restrict__ hbuf) {
    int n0 = blockIdx.x * NB;
    int tid = threadIdx.x;
    int wv = __builtin_amdgcn_readfirstlane(tid >> 6);
    int lane = tid & 63;
    int g = wv >> 2;            // uniform: 0 = layer0, 1 = layer1
    int w = wv & 3;             // uniform: row group
    int quad = lane >> 4;
    int n = lane & 15;          // batch col
    int i0 = 16 * w + quad * 4; // hidden row base of this lane's C-frag rows

    __shared__ short hb0[2][NB][72];   // bf16 h0, double-buffered, stride 72 (bank-safe)
    __shared__ short hb1[2][NB][72];

    for (int idx = tid; idx < 2 * NB * 72; idx += 512) {
        ((short*)hb0)[idx] = 0;
        ((short*)hb1)[idx] = 0;
    }

    // A-fragments (persistent in VGPRs): tiles {w, w+4, w+8} x kc{0,1}
    short8 A0[6], A1[6], A2[6];
    if (g == 0) {
#pragma unroll
        for (int t3 = 0; t3 < 3; t3++)
#pragma unroll
            for (int kc = 0; kc < 2; kc++)
                A0[t3 * 2 + kc] = *(const short8*)(a0 + (((size_t)(w + 4 * t3) * 2 + kc) * 64 + lane) * 8);
    } else {
#pragma unroll
        for (int t3 = 0; t3 < 3; t3++)
#pragma unroll
            for (int kc = 0; kc < 2; kc++) {
                A1[t3 * 2 + kc] = *(const short8*)(a1 + (((size_t)(w + 4 * t3) * 2 + kc) * 64 + lane) * 8);
                A2[t3 * 2 + kc] = *(const short8*)(a2 + (((size_t)(w + 4 * t3) * 2 + kc) * 64 + lane) * 8);
            }
    }
    // biases for this lane's 4 rows
    float bR[4], bZ[4], bN[4], cR[4], cZ[4], cN[4];
#pragma unroll
    for (int r = 0; r < 4; r++) {
        if (g == 0) {
            bR[r] = bhh0[i0 + r]; bZ[r] = bhh0[H + i0 + r]; bN[r] = bhh0[2 * H + i0 + r];
        } else {
            bR[r] = bih1[i0 + r]; bZ[r] = bih1[H + i0 + r]; bN[r] = bih1[2 * H + i0 + r];
            cR[r] = bhh1[i0 + r]; cZ[r] = bhh1[H + i0 + r]; cN[r] = bhh1[2 * H + i0 + r];
        }
    }

    float hprev[4] = {0.f, 0.f, 0.f, 0.f};
    const float* xpB = xp0 + (size_t)(n0 + n) * SEQ * GDIM;
    f32x4 xr_c = {0,0,0,0}, xz_c = {0,0,0,0}, xn_c = {0,0,0,0};
    f32x4 xr_n = {0,0,0,0}, xz_n = {0,0,0,0}, xn_n = {0,0,0,0};
    if (g == 0) {
        xr_c = *(const f32x4*)(xpB + i0);
        xz_c = *(const f32x4*)(xpB + H + i0);
        xn_c = *(const f32x4*)(xpB + 2 * H + i0);
    }
    __syncthreads();

    for (int s = 0; s <= SEQ; s++) {
        int rp = s & 1, wp = (s + 1) & 1;
        if (g == 0 && s + 1 < SEQ) {
            const float* p = xpB + (size_t)(s + 1) * GDIM;
            xr_n = *(const f32x4*)(p + i0);
            xz_n = *(const f32x4*)(p + H + i0);
            xn_n = *(const f32x4*)(p + 2 * H + i0);
        }
        // B-frags from bf16 LDS (B[k][n]: k = kc*32 + quad*8 + j, n = lane&15)
        short8 B0k0 = *(const short8*)&hb0[rp][n][quad * 8];
        short8 B0k1 = *(const short8*)&hb0[rp][n][32 + quad * 8];

        if (g == 0) {
            f32x4 aR = {0,0,0,0}, aZ = {0,0,0,0}, aN = {0,0,0,0};
            aR = __builtin_amdgcn_mfma_f32_16x16x32_bf16(A0[0], B0k0, aR, 0, 0, 0);
            aR = __builtin_amdgcn_mfma_f32_16x16x32_bf16(A0[1], B0k1, aR, 0, 0, 0);
            aZ = __builtin_amdgcn_mfma_f32_16x16x32_bf16(A0[2], B0k0, aZ, 0, 0, 0);
            aZ = __builtin_amdgcn_mfma_f32_16x16x32_bf16(A0[3], B0k1, aZ, 0, 0, 0);
            aN = __builtin_amdgcn_mfma_f32_16x16x32_bf16(A0[4], B0k0, aN, 0, 0, 0);
            aN = __builtin_amdgcn_mfma_f32_16x16x32_bf16(A0[5], B0k1, aN, 0, 0, 0);
            if (s < SEQ) {
                short hq[4];
#pragma unroll
                for (int r = 0; r < 4; r++) {
                    float rg = sigf(xr_c[r] + aR[r] + bR[r]);
                    float zg = sigf(xz_c[r] + aZ[r] + bZ[r]);
                    float ng = tanhfast(xn_c[r] + rg * (aN[r] + bN[r]));
                    hprev[r] = (1.0f - zg) * ng + zg * hprev[r];
                    hq[r] = bf16r(hprev[r]);
                }
                unsigned lo = ((unsigned)(unsigned short)hq[0]) | (((unsigned)(unsigned short)hq[1]) << 16);
                unsigned hi = ((unsigned)(unsigned short)hq[2]) | (((unsigned)(unsigned short)hq[3]) << 16);
                *(uint2*)&hb0[wp][n][i0] = make_uint2(lo, hi);
                xr_c = xr_n; xz_c = xz_n; xn_c = xn_n;
            }
        } else {
            short8 B1k0 = *(const short8*)&hb1[rp][n][quad * 8];
            short8 B1k1 = *(const short8*)&hb1[rp][n][32 + quad * 8];
            f32x4 aIr = {0,0,0,0}, aIz = {0,0,0,0}, aIn = {0,0,0,0};
            f32x4 aHr = {0,0,0,0}, aHz = {0,0,0,0}, aHn = {0,0,0,0};
            aIr = __builtin_amdgcn_mfma_f32_16x16x32_bf16(A1[0], B0k0, aIr, 0, 0, 0);
            aIr = __builtin_amdgcn_mfma_f32_16x16x32_bf16(A1[1], B0k1, aIr, 0, 0, 0);
            aIz = __builtin_amdgcn_mfma_f32_16x16x32_bf16(A1[2], B0k0, aIz, 0, 0, 0);
            aIz = __builtin_amdgcn_mfma_f32_16x16x32_bf16(A1[3], B0k1, aIz, 0, 0, 0);
            aIn = __builtin_amdgcn_mfma_f32_16x16x32_bf16(A1[4], B0k0, aIn, 0, 0, 0);
            aIn = __builtin_amdgcn_mfma_f32_16x16x32_bf16(A1[5], B0k1, aIn, 0, 0, 0);
            aHr = __builtin_amdgcn_mfma_f32_16x16x32_bf16(A2[0], B1k0, aHr, 0, 0, 0);
            aHr = __builtin_amdgcn_mfma_f32_16x16x32_bf16(A2[1], B1k1, aHr, 0, 0, 0);
            aHz = __builtin_amdgcn_mfma_f32_16x16x32_bf16(A2[2], B1k0, aHz, 0, 0, 0);
            aHz = __builtin_amdgcn_mfma_f32_16x16x32_bf16(A2[3], B1k1, aHz, 0, 0, 0);
            aHn = __builtin_amdgcn_mfma_f32_16x16x32_bf16(A2[4], B1k0, aHn, 0, 0, 0);
            aHn = __builtin_amdgcn_mfma_f32_16x16x32_bf16(A2[5], B1k1, aHn, 0, 0, 0);
            if (s >= 1) {
                short hq[4];
                f32x4 hv;
#pragma unroll
                for (int r = 0; r < 4; r++) {
                    float rg = sigf(aIr[r] + bR[r] + aHr[r] + cR[r]);
                    float zg = sigf(aIz[r] + bZ[r] + aHz[r] + cZ[r]);
                    float ng = tanhfast(aIn[r] + bN[r] + rg * (aHn[r] + cN[r]));
                    hprev[r] = (1.0f - zg) * ng + zg * hprev[r];
                    hq[r] = bf16r(hprev[r]);
                    hv[r] = hprev[r];
                }
                unsigned lo = ((unsigned)(unsigned short)hq[0]) | (((unsigned)(unsigned short)hq[1]) << 16);
                unsigned hi = ((unsigned)(unsigned short)hq[2]) | (((unsigned)(unsigned short)hq[3]) << 16);
                *(uint2*)&hb1[wp][n][i0] = make_uint2(lo, hi);
                *(f32x4*)&hbuf[((size_t)(n0 + n) * SEQ + (s - 1)) * H + i0] = hv;
            }
        }
        __syncthreads();
    }
}

// ---------------- MFMA SINDy layer (unchanged from R4) ------------------------------
__global__ __launch_bounds__(512) void sindy_mfma(float* __restrict__ hbuf,
                                                  const short* __restrict__ cpk,
                                                  const short* __restrict__ w1p,
                                                  const short* __restrict__ w2p,
                                                  const float* __restrict__ g1,
                                                  const float* __restrict__ b1n,
                                                  const float* __restrict__ bf1,
                                                  const float* __restrict__ bf2v,
                                                  const float* __restrict__ g2,
                                                  const float* __restrict__ b2n,
                                                  float* __restrict__ out,
                                                  int final_layer) {
    __shared__ float z[64 * 68];
    __shared__ float upd[64 * 68];
    __shared__ float ff[64 * 132];
    __shared__ unsigned kmap[KPAD];
    __shared__ float bfs1[FFD], bfs2[H], g1s[H], b1s[H], g2s[H], b2s[H];

    int tid = threadIdx.x;
    int wv = __builtin_amdgcn_readfirstlane(tid >> 6);
    int lane = tid & 63;
    int row0 = blockIdx.x * 64;

    for (int idx = tid; idx < 64 * 16; idx += 512) {
        int r = idx >> 4, c4 = idx & 15;
        *(f32x4*)&z[r * 68 + c4 * 4] = *(const f32x4*)&hbuf[(size_t)(row0 + r) * H + c4 * 4];
    }
    for (int idx = tid; idx < 64 * 17; idx += 512)
        *(f32x4*)&upd[idx * 4] = (f32x4){0.f, 0.f, 0.f, 0.f};
    if (tid < 64) {
        z[tid * 68 + 64] = 1.0f; z[tid * 68 + 65] = 0.0f;
        z[tid * 68 + 66] = 0.0f; z[tid * 68 + 67] = 0.0f;
    }
    for (int k = tid; k < KPAD; k += 512) {
        unsigned a, b;
        if (k == 0) { a = 64; b = 64; }
        else if (k < 1 + H) { a = (unsigned)(k - 1); b = 64; }
        else if (k < LIBN) {
            int q = k - (1 + H);
            double s = sqrt(16641.0 - 8.0 * (double)q);
            int i = (int)((129.0 - s) * 0.5);
            int base = 64 * i - (i * (i - 1)) / 2;
            a = (unsigned)i; b = (unsigned)(i + (q - base));
        } else { a = 65; b = 65; }
        kmap[k] = (a << 16) | b;
    }
    if (tid < FFD) bfs1[tid] = bf1[tid];
    if (tid < H) {
        bfs2[tid] = bf2v[tid];
        g1s[tid] = g1[tid]; b1s[tid] = b1n[tid];
        g2s[tid] = g2[tid]; b2s[tid] = b2n[tid];
    }
    __syncthreads();

    int kj0 = ((lane >> 4) << 3);
    int m0 = (wv & 3) * 16;
    int m = m0 + (lane & 15);
    int rbase = m0 + ((lane >> 4) << 2);
    int cb16 = lane & 15;
    const float* zrow = &z[m * 68];

    // ---- phase 1: upd = theta @ coef (k-split 2-way) ----
    {
        int p = wv >> 2;
        f32x4 acc[4] = {{0,0,0,0},{0,0,0,0},{0,0,0,0},{0,0,0,0}};
        for (int kc = p; kc < NKC; kc += 2) {
            int kbase = kc * 32 + kj0;
            u32x4 km0 = *(const u32x4*)&kmap[kbase];
            u32x4 km1 = *(const u32x4*)&kmap[kbase + 4];
            short8 af;
            af[0] = bf16r(zrow[km0[0] >> 16] * zrow[km0[0] & 0xffff]);
            af[1] = bf16r(zrow[km0[1] >> 16] * zrow[km0[1] & 0xffff]);
            af[2] = bf16r(zrow[km0[2] >> 16] * zrow[km0[2] & 0xffff]);
            af[3] = bf16r(zrow[km0[3] >> 16] * zrow[km0[3] & 0xffff]);
            af[4] = bf16r(zrow[km1[0] >> 16] * zrow[km1[0] & 0xffff]);
            af[5] = bf16r(zrow[km1[1] >> 16] * zrow[km1[1] & 0xffff]);
            af[6] = bf16r(zrow[km1[2] >> 16] * zrow[km1[2] & 0xffff]);
            af[7] = bf16r(zrow[km1[3] >> 16] * zrow[km1[3] & 0xffff]);
            const short* cb = cpk + ((size_t)(kc * 4) * 64 + lane) * 8;
#pragma unroll
            for (int nt = 0; nt < 4; nt++) {
                short8 bf = *(const short8*)(cb + (size_t)nt * 512);
                acc[nt] = __builtin_amdgcn_mfma_f32_16x16x32_bf16(af, bf, acc[nt], 0, 0, 0);
            }
        }
#pragma unroll
        for (int nt = 0; nt < 4; nt++)
#pragma unroll
            for (int r = 0; r < 4; r++)
                atomicAdd(&upd[(rbase + r) * 68 + nt * 16 + cb16], acc[nt][r]);
    }
    __syncthreads();

    // ---- phase 2: LN1 (wave 0) -> z ----
    if (wv == 0) {
        float v[64];
        float s1 = 0.0f;
#pragma unroll
        for (int c = 0; c < 64; c++) { v[c] = z[lane * 68 + c] + upd[lane * 68 + c]; s1 += v[c]; }
        float mn = s1 * (1.0f / 64.0f);
        float s2 = 0.0f;
#pragma unroll
        for (int c = 0; c < 64; c++) { float d = v[c] - mn; s2 += d * d; }
        float rstd = 1.0f / sqrtf(s2 * (1.0f / 64.0f) + 1e-5f);
#pragma unroll
        for (int c = 0; c < 64; c++)
            z[lane * 68 + c] = (v[c] - mn) * rstd * g1s[c] + b1s[c];
    }
    __syncthreads();

    // ---- phase 3: ff = gelu(LN1 @ W1^T + b1) ----
    {
        int nq = wv >> 2;
        f32x4 acc[4] = {{0,0,0,0},{0,0,0,0},{0,0,0,0},{0,0,0,0}};
#pragma unroll
        for (int kc = 0; kc < 2; kc++) {
            f32x4 za = *(const f32x4*)&z[m * 68 + kc * 32 + kj0];
            f32x4 zb = *(const f32x4*)&z[m * 68 + kc * 32 + kj0 + 4];
            short8 af;
            af[0] = bf16r(za[0]); af[1] = bf16r(za[1]); af[2] = bf16r(za[2]); af[3] = bf16r(za[3]);
            af[4] = bf16r(zb[0]); af[5] = bf16r(zb[1]); af[6] = bf16r(zb[2]); af[7] = bf16r(zb[3]);
#pragma unroll
            for (int t = 0; t < 4; t++) {
                int nt = nq * 4 + t;
                short8 bf = *(const short8*)(w1p + ((size_t)(kc * 8 + nt) * 64 + lane) * 8);
                acc[t] = __builtin_amdgcn_mfma_f32_16x16x32_bf16(af, bf, acc[t], 0, 0, 0);
            }
        }
#pragma unroll
        for (int t = 0; t < 4; t++) {
            int col = (nq * 4 + t) * 16 + cb16;
#pragma unroll
            for (int r = 0; r < 4; r++) {
                float v = acc[t][r] + bfs1[col];
                ff[(rbase + r) * 132 + col] = 0.5f * v * (1.0f + erff(v * 0.70710678118654752f));
            }
        }
    }
    __syncthreads();

    // ---- phase 5: upd = ff @ W2^T + b2 ----
    {
        int nh = wv >> 2;
        f32x4 acc[2] = {{0,0,0,0},{0,0,0,0}};
        const float* frow = &ff[m * 132];
#pragma unroll
        for (int kc = 0; kc < 4; kc++) {
            f32x4 fa = *(const f32x4*)&frow[kc * 32 + kj0];
            f32x4 fb = *(const f32x4*)&frow[kc * 32 + kj0 + 4];
            short8 af;
            af[0] = bf16r(fa[0]); af[1] = bf16r(fa[1]); af[2] = bf16r(fa[2]); af[3] = bf16r(fa[3]);
            af[4] = bf16r(fb[0]); af[5] = bf16r(fb[1]); af[6] = bf16r(fb[2]); af[7] = bf16r(fb[3]);
#pragma unroll
            for (int t = 0; t < 2; t++) {
                int nt = nh * 2 + t;
                short8 bf = *(const short8*)(w2p + ((size_t)(kc * 4 + nt) * 64 + lane) * 8);
                acc[t] = __builtin_amdgcn_mfma_f32_16x16x32_bf16(af, bf, acc[t], 0, 0, 0);
            }
        }
#pragma unroll
        for (int t = 0; t < 2; t++) {
            int col = (nh * 2 + t) * 16 + cb16;
#pragma unroll
            for (int r = 0; r < 4; r++)
                upd[(rbase + r) * 68 + col] = acc[t][r] + bfs2[col];
        }
    }
    __syncthreads();

    // ---- phase 6: LN2 + write (wave 0) ----
    if (wv == 0) {
        float v[64];
        float s1 = 0.0f;
#pragma unroll
        for (int c = 0; c < 64; c++) { v[c] = z[lane * 68 + c] + upd[lane * 68 + c]; s1 += v[c]; }
        float mn = s1 * (1.0f / 64.0f);
        float s2 = 0.0f;
#pragma unroll
        for (int c = 0; c < 64; c++) { float d = v[c] - mn; s2 += d * d; }
        float rstd = 1.0f / sqrtf(s2 * (1.0f / 64.0f) + 1e-5f);
        int row = row0 + lane;
#pragma unroll
        for (int c = 0; c < 64; c++) {
            float res = (v[c] - mn) * rstd * g2s[c] + b2s[c];
            if (!final_layer) {
                hbuf[(size_t)row * H + c] = res;
            } else {
                out[(size_t)row * H + c] = res;
                if (row % SEQ == SEQ - 1)
                    out[(size_t)NROW * H + (row / SEQ) * H + c] = res;
            }
        }
    }
}

extern "C" void kernel_launch(void* const* d_in, const int* in_sizes, int n_in,
                              void* d_out, int out_size, void* d_ws, size_t ws_size,
                              hipStream_t stream) {
    const float* x    = (const float*)d_in[0];
    const float* wih0 = (const float*)d_in[1];
    const float* whh0 = (const float*)d_in[2];
    const float* bih0 = (const float*)d_in[3];
    const float* bhh0 = (const float*)d_in[4];
    const float* wih1 = (const float*)d_in[5];
    const float* whh1 = (const float*)d_in[6];
    const float* bih1 = (const float*)d_in[7];
    const float* bhh1 = (const float*)d_in[8];
    const float* coeffs = (const float*)d_in[9];
    const float* ln1g = (const float*)d_in[10];
    const float* ln1b = (const float*)d_in[11];
    const float* w1   = (const float*)d_in[12];
    const float* b1   = (const float*)d_in[13];
    const float* w2   = (const float*)d_in[14];
    const float* b2   = (const float*)d_in[15];
    const float* ln2g = (const float*)d_in[16];
    const float* ln2b = (const float*)d_in[17];

    float* out = (float*)d_out;
    float* ws  = (float*)d_ws;
    float* xp0 = ws;                               // 16000*192 = 3,072,000 floats
    float* wtp = ws + (size_t)NROW * GDIM;         // 24,576 floats
    short* bfa = (short*)(wtp + GDIM * DM);        // bf16 fragment area
    short* cpk[2] = { bfa, bfa + 139264 };
    short* w1pk[2] = { bfa + 2 * 139264, bfa + 2 * 139264 + 8192 };
    short* w2pk[2] = { bfa + 2 * 139264 + 2 * 8192, bfa + 2 * 139264 + 3 * 8192 };
    short* ga0 = bfa + 2 * 139264 + 4 * 8192;      // GRU A-frags: 3 x 12288 shorts
    short* ga1 = ga0 + 12288;
    short* ga2 = ga1 + 12288;
    float* hbuf = out;                             // reuse first 1,024,000 floats of d_out

    pack_wih0<<<(GDIM * DM + 255) / 256, 256, 0, stream>>>(wih0, wtp);
    for (int l = 0; l < 2; l++) {
        pack_coef_frag<<<139264 / 256, 256, 0, stream>>>(coeffs + (size_t)l * LIBN * H, cpk[l]);
        pack_w1_frag<<<8192 / 256, 256, 0, stream>>>(w1 + (size_t)l * FFD * H, w1pk[l]);
        pack_w2_frag<<<8192 / 256, 256, 0, stream>>>(w2 + (size_t)l * H * FFD, w2pk[l]);
    }
    pack_gruw_frag<<<48, 256, 0, stream>>>(whh0, ga0);
    pack_gruw_frag<<<48, 256, 0, stream>>>(wih1, ga1);
    pack_gruw_frag<<<48, 256, 0, stream>>>(whh1, ga2);
    xp0_gemm<<<NROW / 64, 192, 0, stream>>>(x, wtp, bih0, xp0);
    gru_mfma<<<BSZ / NB, 512, 0, stream>>>(xp0, ga0, ga1, ga2, bhh0, bih1, bhh1, hbuf);
    for (int l = 0; l < 2; l++) {
        sindy_mfma<<<NROW / 64, 512, 0, stream>>>(
            hbuf, cpk[l], w1pk[l], w2pk[l],
            ln1g + l * H, ln1b + l * H, b1 + l * FFD,
            b2 + l * H, ln2g + l * H, ln2b + l * H,
            out, l == 1);
    }
}

// Round 6
// 553.432 us; speedup vs baseline: 1.4539x; 1.4539x over previous
//
#include <hip/hip_runtime.h>
#include <hip/hip_bf16.h>
#include <math.h>

#define H 64
#define DM 128
#define GDIM 192      // 3*H
#define BSZ 32
#define SEQ 500
#define NROW (BSZ*SEQ)  // 16000
#define LIBN 2145
#define FFD 128
#define KPAD 2176     // 68*32 (theta K padded)
#define NKC 68        // K chunks of 32

typedef __attribute__((ext_vector_type(8))) short short8;   // bf16x8 MFMA operand
typedef __attribute__((ext_vector_type(4))) float f32x4;    // MFMA accumulator
typedef __attribute__((ext_vector_type(4))) unsigned u32x4;

__device__ __forceinline__ float sigf(float x) {
    return 1.0f / (1.0f + __expf(-x));
}
__device__ __forceinline__ float tanhfast(float x) {
    x = fminf(fmaxf(x, -15.0f), 15.0f);
    float t = __expf(-2.0f * x);
    return (1.0f - t) / (1.0f + t);
}
__device__ __forceinline__ short bf16r(float f) {   // fp32 -> bf16 rne
    unsigned u = __float_as_uint(f);
    unsigned r = (u + 0x7fffu + ((u >> 16) & 1u)) >> 16;
    return (short)r;
}

// ---------------- pack Wih0 (192,128) -> WTp[k4][g][e] for coalesced float4 loads ----
__global__ void pack_wih0(const float* __restrict__ w, float* __restrict__ wt) {
    int idx = blockIdx.x * 256 + threadIdx.x;
    if (idx >= GDIM * DM) return;
    int e  = idx & 3;
    int g  = (idx >> 2) % GDIM;
    int k4 = idx / (GDIM * 4);
    wt[idx] = w[g * DM + k4 * 4 + e];
}

// ---- prepack coef (2145x64, zero-pad to 2176) into bf16 B-fragment-linear order ----
__global__ void pack_coef_frag(const float* __restrict__ coef, short* __restrict__ cp) {
    int idx = blockIdx.x * 256 + threadIdx.x;           // 68*4*64*8 = 139264
    int j = idx & 7, lane = (idx >> 3) & 63, nt = (idx >> 9) & 3, kc = idx >> 11;
    int k = kc * 32 + ((lane >> 4) << 3) + j;
    int c = nt * 16 + (lane & 15);
    float v = (k < LIBN) ? coef[(size_t)k * H + c] : 0.0f;
    cp[idx] = bf16r(v);
}
// ---- W1 (128,64): B = W1^T (K=64,N=128) ----
__global__ void pack_w1_frag(const float* __restrict__ w1, short* __restrict__ wp) {
    int idx = blockIdx.x * 256 + threadIdx.x;           // 2*8*64*8 = 8192
    int j = idx & 7, lane = (idx >> 3) & 63, nt = (idx >> 9) & 7, kc = idx >> 12;
    int k = kc * 32 + ((lane >> 4) << 3) + j;
    int n = nt * 16 + (lane & 15);
    wp[idx] = bf16r(w1[(size_t)n * H + k]);
}
// ---- W2 (64,128): B = W2^T (K=128,N=64) ----
__global__ void pack_w2_frag(const float* __restrict__ w2, short* __restrict__ wp) {
    int idx = blockIdx.x * 256 + threadIdx.x;           // 4*4*64*8 = 8192
    int j = idx & 7, lane = (idx >> 3) & 63, nt = (idx >> 9) & 3, kc = idx >> 11;
    int k = kc * 32 + ((lane >> 4) << 3) + j;
    int n = nt * 16 + (lane & 15);
    wp[idx] = bf16r(w2[(size_t)n * FFD + k]);
}

// ---------------- xp0 = x @ Wih0^T + bih0, stored in GRU chunk layout ----------------
// xpT[((b*125 + sc)*192 + g)*4 + e] where s = sc*4 + e: gru wave-0 lane loads one
// f32x4 = 4 consecutive steps of one gate row -> 3 b128 loads per 4 steps.
__global__ __launch_bounds__(192, 2) void xp0_gemm(const float* __restrict__ x,
                                                   const float* __restrict__ wtp,
                                                   const float* __restrict__ bih0,
                                                   float* __restrict__ xpT) {
    __shared__ float xs[64][DM];
    int rb = blockIdx.x * 64;
    for (int idx = threadIdx.x; idx < 64 * 32; idx += 192) {
        int r = idx >> 5, k4 = idx & 31;
        ((f32x4*)xs[r])[k4] = ((const f32x4*)(x + (size_t)(rb + r) * DM))[k4];
    }
    __syncthreads();
    int g = threadIdx.x;
    float bias = bih0[g];
    float acc[64];
#pragma unroll
    for (int r = 0; r < 64; r++) acc[r] = bias;
    for (int k4 = 0; k4 < 32; k4++) {
        f32x4 w4 = ((const f32x4*)wtp)[k4 * GDIM + g];
#pragma unroll
        for (int r = 0; r < 64; r++) {
            f32x4 xv = ((f32x4*)xs[r])[k4];
            acc[r] += w4[0] * xv[0] + w4[1] * xv[1] + w4[2] * xv[2] + w4[3] * xv[3];
        }
    }
    for (int r = 0; r < 64; r++) {
        int row = rb + r;
        int bb = row / 500;
        int ss = row - bb * 500;
        xpT[(((size_t)bb * 125 + (ss >> 2)) * GDIM + g) * 4 + (ss & 3)] = acc[r];
    }
}

// ---------------- fused 2-layer GRU scan: R3 12-wave structure + amortized I/O -------
// Wave (m = wv%3, q = wv/3) computes K-chunk [16q,16q+16) of matvec m (m0: Whh0@h0,
// m1: Wih1@h0, m2: Whh1@h1); lane i owns rows {i,64+i,128+i}. Gate waves: wv0 = layer0,
// wv2 = layer1 (one step skewed). NEW: xp inputs read 2 chunks (8 steps) ahead into a
// 4-buffer register ring (static indices via 4x4 unroll), h1 outputs buffered 4 steps
// in regs -> the per-barrier vmcnt(0) drain happens once per 8 (loads) / 4 (stores)
// steps instead of every step.
__global__ __launch_bounds__(768, 3) void gru_fused(const float* __restrict__ xpT,
                                                    const float* __restrict__ whh0,
                                                    const float* __restrict__ bhh0,
                                                    const float* __restrict__ wih1,
                                                    const float* __restrict__ bih1,
                                                    const float* __restrict__ whh1,
                                                    const float* __restrict__ bhh1,
                                                    float* __restrict__ hbuf) {
    int b = blockIdx.x;
    int tid = threadIdx.x;
    int wv = __builtin_amdgcn_readfirstlane(tid >> 6);
    int lane = tid & 63;
    int m = wv % 3;
    int q = wv / 3;
    int k0 = q * 16;

    __shared__ __align__(16) float h0s[H];
    __shared__ __align__(16) float h1s[H];
    __shared__ float part[3][4][GDIM];

    if (tid < H) { h0s[tid] = 0.0f; h1s[tid] = 0.0f; }

    const float* W = (m == 0) ? whh0 : (m == 1) ? wih1 : whh1;
    float wr[16], wz[16], wn[16];
#pragma unroll
    for (int k4 = 0; k4 < 4; k4++) {
        f32x4 a = ((const f32x4*)(W + (size_t)lane * H + k0))[k4];
        f32x4 c = ((const f32x4*)(W + (size_t)(H + lane) * H + k0))[k4];
        f32x4 d = ((const f32x4*)(W + (size_t)(2 * H + lane) * H + k0))[k4];
        wr[4*k4] = a[0]; wr[4*k4+1] = a[1]; wr[4*k4+2] = a[2]; wr[4*k4+3] = a[3];
        wz[4*k4] = c[0]; wz[4*k4+1] = c[1]; wz[4*k4+2] = c[2]; wz[4*k4+3] = c[3];
        wn[4*k4] = d[0]; wn[4*k4+1] = d[1]; wn[4*k4+2] = d[2]; wn[4*k4+3] = d[3];
    }

    float b0r = 0, b0z = 0, b0n = 0;
    float b1ir = 0, b1iz = 0, b1in = 0, b1hr = 0, b1hz = 0, b1hn = 0;
    float hreg0 = 0.0f, hreg1 = 0.0f;
    float hb4[4] = {0.f, 0.f, 0.f, 0.f};
    f32x4 xc[4][3];
    const float* xpB = xpT + (size_t)b * 125 * GDIM * 4;

    if (wv == 0) {
        b0r = bhh0[lane]; b0z = bhh0[H + lane]; b0n = bhh0[2 * H + lane];
#pragma unroll
        for (int g3 = 0; g3 < 3; g3++) {
            xc[0][g3] = *(const f32x4*)(xpB + ((size_t)0 * GDIM + g3 * 64 + lane) * 4);
            xc[1][g3] = *(const f32x4*)(xpB + ((size_t)1 * GDIM + g3 * 64 + lane) * 4);
        }
    } else if (wv == 2) {
        b1ir = bih1[lane]; b1iz = bih1[H + lane]; b1in = bih1[2 * H + lane];
        b1hr = bhh1[lane]; b1hz = bhh1[H + lane]; b1hn = bhh1[2 * H + lane];
    }
    __syncthreads();

    auto loadch = [&](int c, int buf) {
        if (c < 125) {
#pragma unroll
            for (int g3 = 0; g3 < 3; g3++)
                xc[buf][g3] = *(const f32x4*)(xpB + ((size_t)c * GDIM + g3 * 64 + lane) * 4);
        }
    };

    auto step = [&](int s, int e, float xr, float xz, float xn) {
        // phase 1: partial matvec over K-chunk [k0, k0+16); h reads are wave-uniform
        // addresses -> LDS broadcast (no bandwidth serialization).
        const float* hv = (m == 2) ? h1s : h0s;
        float ar = 0, az = 0, an = 0;
#pragma unroll
        for (int t4 = 0; t4 < 4; t4++) {
            f32x4 h4 = ((const f32x4*)(hv + k0))[t4];
            ar += wr[4*t4] * h4[0] + wr[4*t4+1] * h4[1] + wr[4*t4+2] * h4[2] + wr[4*t4+3] * h4[3];
            az += wz[4*t4] * h4[0] + wz[4*t4+1] * h4[1] + wz[4*t4+2] * h4[2] + wz[4*t4+3] * h4[3];
            an += wn[4*t4] * h4[0] + wn[4*t4+1] * h4[1] + wn[4*t4+2] * h4[2] + wn[4*t4+3] * h4[3];
        }
        part[m][q][lane] = ar;
        part[m][q][H + lane] = az;
        part[m][q][2 * H + lane] = an;
        __syncthreads();

        // phase 2: gates
        if (wv == 0) {
            if (s < SEQ) {
                float gr = b0r, gz = b0z, gn = b0n;
#pragma unroll
                for (int qq = 0; qq < 4; qq++) {
                    gr += part[0][qq][lane];
                    gz += part[0][qq][H + lane];
                    gn += part[0][qq][2 * H + lane];
                }
                float rg = sigf(xr + gr);
                float zg = sigf(xz + gz);
                float ng = tanhfast(xn + rg * gn);
                hreg0 = (1.0f - zg) * ng + zg * hreg0;
                h0s[lane] = hreg0;
            }
        } else if (wv == 2) {
            if (s >= 1) {
                float xr1 = b1ir, xz1 = b1iz, xn1 = b1in;
                float gr1 = b1hr, gz1 = b1hz, gn1 = b1hn;
#pragma unroll
                for (int qq = 0; qq < 4; qq++) {
                    xr1 += part[1][qq][lane];
                    xz1 += part[1][qq][H + lane];
                    xn1 += part[1][qq][2 * H + lane];
                    gr1 += part[2][qq][lane];
                    gz1 += part[2][qq][H + lane];
                    gn1 += part[2][qq][2 * H + lane];
                }
                float rg = sigf(xr1 + gr1);
                float zg = sigf(xz1 + gz1);
                float ng = tanhfast(xn1 + rg * gn1);
                hreg1 = (1.0f - zg) * ng + zg * hreg1;
                h1s[lane] = hreg1;
                hb4[(e + 3) & 3] = hreg1;                 // h1[s-1], (s-1)&3 == (e+3)&3
                if (e == 0) {                              // s in {4,8,...,500}: flush h1[s-4..s-1]
                    float* dst = hbuf + ((size_t)b * SEQ + (s - 4)) * H + lane;
#pragma unroll
                    for (int t = 0; t < 4; t++) dst[t * H] = hb4[t];
                }
            }
        }
        __syncthreads();
    };

    for (int scb = 0; scb < 31; scb++) {
#pragma unroll
        for (int sci = 0; sci < 4; sci++) {
            int sc = scb * 4 + sci;
            if (wv == 0 && (sci & 1) == 0) {
                loadch(sc + 2, (sci + 2) & 3);
                loadch(sc + 3, (sci + 3) & 3);
            }
            int s0 = sc * 4;
            step(s0 + 0, 0, xc[sci][0][0], xc[sci][1][0], xc[sci][2][0]);
            step(s0 + 1, 1, xc[sci][0][1], xc[sci][1][1], xc[sci][2][1]);
            step(s0 + 2, 2, xc[sci][0][2], xc[sci][1][2], xc[sci][2][2]);
            step(s0 + 3, 3, xc[sci][0][3], xc[sci][1][3], xc[sci][2][3]);
        }
    }
    {   // sc = 124 (buf 0, loaded at sc=122)
        step(496, 0, xc[0][0][0], xc[0][1][0], xc[0][2][0]);
        step(497, 1, xc[0][0][1], xc[0][1][1], xc[0][2][1]);
        step(498, 2, xc[0][0][2], xc[0][1][2], xc[0][2][2]);
        step(499, 3, xc[0][0][3], xc[0][1][3], xc[0][2][3]);
    }
    // tail s = 500: produces h1[499] and flushes h1[496..499]
    step(500, 0, 0.0f, 0.0f, 0.0f);
}

// ---------------- MFMA SINDy layer (unchanged from R4) ------------------------------
__global__ __launch_bounds__(512) void sindy_mfma(float* __restrict__ hbuf,
                                                  const short* __restrict__ cpk,
                                                  const short* __restrict__ w1p,
                                                  const short* __restrict__ w2p,
                                                  const float* __restrict__ g1,
                                                  const float* __restrict__ b1n,
                                                  const float* __restrict__ bf1,
                                                  const float* __restrict__ bf2v,
                                                  const float* __restrict__ g2,
                                                  const float* __restrict__ b2n,
                                                  float* __restrict__ out,
                                                  int final_layer) {
    __shared__ float z[64 * 68];
    __shared__ float upd[64 * 68];
    __shared__ float ff[64 * 132];
    __shared__ unsigned kmap[KPAD];
    __shared__ float bfs1[FFD], bfs2[H], g1s[H], b1s[H], g2s[H], b2s[H];

    int tid = threadIdx.x;
    int wv = __builtin_amdgcn_readfirstlane(tid >> 6);
    int lane = tid & 63;
    int row0 = blockIdx.x * 64;

    for (int idx = tid; idx < 64 * 16; idx += 512) {
        int r = idx >> 4, c4 = idx & 15;
        *(f32x4*)&z[r * 68 + c4 * 4] = *(const f32x4*)&hbuf[(size_t)(row0 + r) * H + c4 * 4];
    }
    for (int idx = tid; idx < 64 * 17; idx += 512)
        *(f32x4*)&upd[idx * 4] = (f32x4){0.f, 0.f, 0.f, 0.f};
    if (tid < 64) {
        z[tid * 68 + 64] = 1.0f; z[tid * 68 + 65] = 0.0f;
        z[tid * 68 + 66] = 0.0f; z[tid * 68 + 67] = 0.0f;
    }
    for (int k = tid; k < KPAD; k += 512) {
        unsigned a, b;
        if (k == 0) { a = 64; b = 64; }
        else if (k < 1 + H) { a = (unsigned)(k - 1); b = 64; }
        else if (k < LIBN) {
            int qq = k - (1 + H);
            double s = sqrt(16641.0 - 8.0 * (double)qq);
            int i = (int)((129.0 - s) * 0.5);
            int base = 64 * i - (i * (i - 1)) / 2;
            a = (unsigned)i; b = (unsigned)(i + (qq - base));
        } else { a = 65; b = 65; }
        kmap[k] = (a << 16) | b;
    }
    if (tid < FFD) bfs1[tid] = bf1[tid];
    if (tid < H) {
        bfs2[tid] = bf2v[tid];
        g1s[tid] = g1[tid]; b1s[tid] = b1n[tid];
        g2s[tid] = g2[tid]; b2s[tid] = b2n[tid];
    }
    __syncthreads();

    int kj0 = ((lane >> 4) << 3);
    int m0 = (wv & 3) * 16;
    int m = m0 + (lane & 15);
    int rbase = m0 + ((lane >> 4) << 2);
    int cb16 = lane & 15;
    const float* zrow = &z[m * 68];

    // ---- phase 1: upd = theta @ coef (k-split 2-way) ----
    {
        int p = wv >> 2;
        f32x4 acc[4] = {{0,0,0,0},{0,0,0,0},{0,0,0,0},{0,0,0,0}};
        for (int kc = p; kc < NKC; kc += 2) {
            int kbase = kc * 32 + kj0;
            u32x4 km0 = *(const u32x4*)&kmap[kbase];
            u32x4 km1 = *(const u32x4*)&kmap[kbase + 4];
            short8 af;
            af[0] = bf16r(zrow[km0[0] >> 16] * zrow[km0[0] & 0xffff]);
            af[1] = bf16r(zrow[km0[1] >> 16] * zrow[km0[1] & 0xffff]);
            af[2] = bf16r(zrow[km0[2] >> 16] * zrow[km0[2] & 0xffff]);
            af[3] = bf16r(zrow[km0[3] >> 16] * zrow[km0[3] & 0xffff]);
            af[4] = bf16r(zrow[km1[0] >> 16] * zrow[km1[0] & 0xffff]);
            af[5] = bf16r(zrow[km1[1] >> 16] * zrow[km1[1] & 0xffff]);
            af[6] = bf16r(zrow[km1[2] >> 16] * zrow[km1[2] & 0xffff]);
            af[7] = bf16r(zrow[km1[3] >> 16] * zrow[km1[3] & 0xffff]);
            const short* cb = cpk + ((size_t)(kc * 4) * 64 + lane) * 8;
#pragma unroll
            for (int nt = 0; nt < 4; nt++) {
                short8 bf = *(const short8*)(cb + (size_t)nt * 512);
                acc[nt] = __builtin_amdgcn_mfma_f32_16x16x32_bf16(af, bf, acc[nt], 0, 0, 0);
            }
        }
#pragma unroll
        for (int nt = 0; nt < 4; nt++)
#pragma unroll
            for (int r = 0; r < 4; r++)
                atomicAdd(&upd[(rbase + r) * 68 + nt * 16 + cb16], acc[nt][r]);
    }
    __syncthreads();

    // ---- phase 2: LN1 (wave 0) -> z ----
    if (wv == 0) {
        float v[64];
        float s1 = 0.0f;
#pragma unroll
        for (int c = 0; c < 64; c++) { v[c] = z[lane * 68 + c] + upd[lane * 68 + c]; s1 += v[c]; }
        float mn = s1 * (1.0f / 64.0f);
        float s2 = 0.0f;
#pragma unroll
        for (int c = 0; c < 64; c++) { float d = v[c] - mn; s2 += d * d; }
        float rstd = 1.0f / sqrtf(s2 * (1.0f / 64.0f) + 1e-5f);
#pragma unroll
        for (int c = 0; c < 64; c++)
            z[lane * 68 + c] = (v[c] - mn) * rstd * g1s[c] + b1s[c];
    }
    __syncthreads();

    // ---- phase 3: ff = gelu(LN1 @ W1^T + b1) ----
    {
        int nq = wv >> 2;
        f32x4 acc[4] = {{0,0,0,0},{0,0,0,0},{0,0,0,0},{0,0,0,0}};
#pragma unroll
        for (int kc = 0; kc < 2; kc++) {
            f32x4 za = *(const f32x4*)&z[m * 68 + kc * 32 + kj0];
            f32x4 zb = *(const f32x4*)&z[m * 68 + kc * 32 + kj0 + 4];
            short8 af;
            af[0] = bf16r(za[0]); af[1] = bf16r(za[1]); af[2] = bf16r(za[2]); af[3] = bf16r(za[3]);
            af[4] = bf16r(zb[0]); af[5] = bf16r(zb[1]); af[6] = bf16r(zb[2]); af[7] = bf16r(zb[3]);
#pragma unroll
            for (int t = 0; t < 4; t++) {
                int nt = nq * 4 + t;
                short8 bf = *(const short8*)(w1p + ((size_t)(kc * 8 + nt) * 64 + lane) * 8);
                acc[t] = __builtin_amdgcn_mfma_f32_16x16x32_bf16(af, bf, acc[t], 0, 0, 0);
            }
        }
#pragma unroll
        for (int t = 0; t < 4; t++) {
            int col = (nq * 4 + t) * 16 + cb16;
#pragma unroll
            for (int r = 0; r < 4; r++) {
                float v = acc[t][r] + bfs1[col];
                ff[(rbase + r) * 132 + col] = 0.5f * v * (1.0f + erff(v * 0.70710678118654752f));
            }
        }
    }
    __syncthreads();

    // ---- phase 5: upd = ff @ W2^T + b2 ----
    {
        int nh = wv >> 2;
        f32x4 acc[2] = {{0,0,0,0},{0,0,0,0}};
        const float* frow = &ff[m * 132];
#pragma unroll
        for (int kc = 0; kc < 4; kc++) {
            f32x4 fa = *(const f32x4*)&frow[kc * 32 + kj0];
            f32x4 fb = *(const f32x4*)&frow[kc * 32 + kj0 + 4];
            short8 af;
            af[0] = bf16r(fa[0]); af[1] = bf16r(fa[1]); af[2] = bf16r(fa[2]); af[3] = bf16r(fa[3]);
            af[4] = bf16r(fb[0]); af[5] = bf16r(fb[1]); af[6] = bf16r(fb[2]); af[7] = bf16r(fb[3]);
#pragma unroll
            for (int t = 0; t < 2; t++) {
                int nt = nh * 2 + t;
                short8 bf = *(const short8*)(w2p + ((size_t)(kc * 4 + nt) * 64 + lane) * 8);
                acc[t] = __builtin_amdgcn_mfma_f32_16x16x32_bf16(af, bf, acc[t], 0, 0, 0);
            }
        }
#pragma unroll
        for (int t = 0; t < 2; t++) {
            int col = (nh * 2 + t) * 16 + cb16;
#pragma unroll
            for (int r = 0; r < 4; r++)
                upd[(rbase + r) * 68 + col] = acc[t][r] + bfs2[col];
        }
    }
    __syncthreads();

    // ---- phase 6: LN2 + write (wave 0) ----
    if (wv == 0) {
        float v[64];
        float s1 = 0.0f;
#pragma unroll
        for (int c = 0; c < 64; c++) { v[c] = z[lane * 68 + c] + upd[lane * 68 + c]; s1 += v[c]; }
        float mn = s1 * (1.0f / 64.0f);
        float s2 = 0.0f;
#pragma unroll
        for (int c = 0; c < 64; c++) { float d = v[c] - mn; s2 += d * d; }
        float rstd = 1.0f / sqrtf(s2 * (1.0f / 64.0f) + 1e-5f);
        int row = row0 + lane;
#pragma unroll
        for (int c = 0; c < 64; c++) {
            float res = (v[c] - mn) * rstd * g2s[c] + b2s[c];
            if (!final_layer) {
                hbuf[(size_t)row * H + c] = res;
            } else {
                out[(size_t)row * H + c] = res;
                if (row % SEQ == SEQ - 1)
                    out[(size_t)NROW * H + (row / SEQ) * H + c] = res;
            }
        }
    }
}

extern "C" void kernel_launch(void* const* d_in, const int* in_sizes, int n_in,
                              void* d_out, int out_size, void* d_ws, size_t ws_size,
                              hipStream_t stream) {
    const float* x    = (const float*)d_in[0];
    const float* wih0 = (const float*)d_in[1];
    const float* whh0 = (const float*)d_in[2];
    const float* bih0 = (const float*)d_in[3];
    const float* bhh0 = (const float*)d_in[4];
    const float* wih1 = (const float*)d_in[5];
    const float* whh1 = (const float*)d_in[6];
    const float* bih1 = (const float*)d_in[7];
    const float* bhh1 = (const float*)d_in[8];
    const float* coeffs = (const float*)d_in[9];
    const float* ln1g = (const float*)d_in[10];
    const float* ln1b = (const float*)d_in[11];
    const float* w1   = (const float*)d_in[12];
    const float* b1   = (const float*)d_in[13];
    const float* w2   = (const float*)d_in[14];
    const float* b2   = (const float*)d_in[15];
    const float* ln2g = (const float*)d_in[16];
    const float* ln2b = (const float*)d_in[17];

    float* out = (float*)d_out;
    float* ws  = (float*)d_ws;
    float* xpT = ws;                               // 16000*192 = 3,072,000 floats
    float* wtp = ws + (size_t)NROW * GDIM;         // 24,576 floats
    short* bfa = (short*)(wtp + GDIM * DM);        // bf16 fragment area
    short* cpk[2] = { bfa, bfa + 139264 };
    short* w1pk[2] = { bfa + 2 * 139264, bfa + 2 * 139264 + 8192 };
    short* w2pk[2] = { bfa + 2 * 139264 + 2 * 8192, bfa + 2 * 139264 + 3 * 8192 };
    float* hbuf = out;                             // reuse first 1,024,000 floats of d_out

    pack_wih0<<<(GDIM * DM + 255) / 256, 256, 0, stream>>>(wih0, wtp);
    for (int l = 0; l < 2; l++) {
        pack_coef_frag<<<139264 / 256, 256, 0, stream>>>(coeffs + (size_t)l * LIBN * H, cpk[l]);
        pack_w1_frag<<<8192 / 256, 256, 0, stream>>>(w1 + (size_t)l * FFD * H, w1pk[l]);
        pack_w2_frag<<<8192 / 256, 256, 0, stream>>>(w2 + (size_t)l * H * FFD, w2pk[l]);
    }
    xp0_gemm<<<NROW / 64, 192, 0, stream>>>(x, wtp, bih0, xpT);
    gru_fused<<<BSZ, 768, 0, stream>>>(xpT, whh0, bhh0, wih1, bih1, whh1, bhh1, hbuf);
    for (int l = 0; l < 2; l++) {
        sindy_mfma<<<NROW / 64, 512, 0, stream>>>(
            hbuf, cpk[l], w1pk[l], w2pk[l],
            ln1g + l * H, ln1b + l * H, b1 + l * FFD,
            b2 + l * H, ln2g + l * H, ln2b + l * H,
            out, l == 1);
    }
}